// Round 1
// baseline (1840.688 us; speedup 1.0000x reference)
//
#include <hip/hip_runtime.h>
#include <hip/hip_bf16.h>
#include <math.h>

// Problem constants
#define T_SEQ 2048
#define DMODEL 2048
#define NH 16
#define NKV 4
#define DH 128
#define RANK 32

// ---------------------------------------------------------------------------
// Generic fp32 tiled GEMM body: C[M,N] = A[M,K] @ B[K,N], all row-major.
// BM=BN=128, BK=8, 256 threads, 8x8 register tile per thread.
// Requires M%128==0, N%128==0 (for the tile this block covers), K%8==0.
// ---------------------------------------------------------------------------
__device__ __forceinline__ void gemm_tile_body(
    const float* __restrict__ A, int lda,
    const float* __restrict__ B, int ldb,
    float* __restrict__ C, int ldc,
    int Kdim, int m0, int n0,
    float (*As)[132], float (*Bs)[128])
{
  const int tid = threadIdx.x;
  const int tx = tid & 15;   // col group
  const int ty = tid >> 4;   // row group
  float acc[8][8];
  #pragma unroll
  for (int i = 0; i < 8; ++i)
    #pragma unroll
    for (int j = 0; j < 8; ++j) acc[i][j] = 0.f;

  const int ar = tid >> 1;           // 0..127 (A tile row)
  const int ak = (tid & 1) * 4;      // 0 or 4 (A tile k)
  const int bk = tid >> 5;           // 0..7   (B tile k)
  const int bc = (tid & 31) * 4;     // 0..124 (B tile col)

  for (int k0 = 0; k0 < Kdim; k0 += 8) {
    __syncthreads();
    float4 av = *(const float4*)(A + (size_t)(m0 + ar) * lda + k0 + ak);
    As[ak + 0][ar] = av.x; As[ak + 1][ar] = av.y;
    As[ak + 2][ar] = av.z; As[ak + 3][ar] = av.w;
    *(float4*)&Bs[bk][bc] = *(const float4*)(B + (size_t)(k0 + bk) * ldb + n0 + bc);
    __syncthreads();
    #pragma unroll
    for (int k = 0; k < 8; ++k) {
      float4 a0 = *(const float4*)&As[k][ty * 8];
      float4 a1 = *(const float4*)&As[k][ty * 8 + 4];
      float4 b0 = *(const float4*)&Bs[k][tx * 8];
      float4 b1 = *(const float4*)&Bs[k][tx * 8 + 4];
      float a[8] = {a0.x, a0.y, a0.z, a0.w, a1.x, a1.y, a1.z, a1.w};
      float b[8] = {b0.x, b0.y, b0.z, b0.w, b1.x, b1.y, b1.z, b1.w};
      #pragma unroll
      for (int i = 0; i < 8; ++i)
        #pragma unroll
        for (int j = 0; j < 8; ++j)
          acc[i][j] = fmaf(a[i], b[j], acc[i][j]);
    }
  }
  #pragma unroll
  for (int i = 0; i < 8; ++i) {
    float* crow = C + (size_t)(m0 + ty * 8 + i) * ldc + n0 + tx * 8;
    float4 c0 = {acc[i][0], acc[i][1], acc[i][2], acc[i][3]};
    float4 c1 = {acc[i][4], acc[i][5], acc[i][6], acc[i][7]};
    *(float4*)crow = c0;
    *(float4*)(crow + 4) = c1;
  }
}

// Fused QKV projection: grid (24,16). bx<16 -> Wq, bx<20 -> Wk, else Wv.
__global__ __launch_bounds__(256) void gemm_qkv_kernel(
    const float* __restrict__ x, const float* __restrict__ Wq,
    const float* __restrict__ Wk, const float* __restrict__ Wv,
    float* __restrict__ Q, float* __restrict__ K, float* __restrict__ V)
{
  __shared__ float As[8][132];
  __shared__ float Bs[8][128];
  const int bx = blockIdx.x, by = blockIdx.y;
  const float* B; float* C; int ldb, n0;
  if (bx < 16)      { B = Wq; C = Q; ldb = 2048; n0 = bx * 128; }
  else if (bx < 20) { B = Wk; C = K; ldb = 512;  n0 = (bx - 16) * 128; }
  else              { B = Wv; C = V; ldb = 512;  n0 = (bx - 20) * 128; }
  gemm_tile_body(x, 2048, B, ldb, C, ldb, 2048, by * 128, n0, As, Bs);
}

// Output projection: out = AO @ Wo, grid (16,16)
__global__ __launch_bounds__(256) void gemm_out_kernel(
    const float* __restrict__ AO, const float* __restrict__ Wo,
    float* __restrict__ Out)
{
  __shared__ float As[8][132];
  __shared__ float Bs[8][128];
  gemm_tile_body(AO, 2048, Wo, 2048, Out, 2048, 2048,
                 blockIdx.y * 128, blockIdx.x * 128, As, Bs);
}

// Low-rank projections A = x@WA, Bm = x@WB (N=32 each), fused. grid 32 blocks.
__global__ __launch_bounds__(256) void gemm_ab_kernel(
    const float* __restrict__ x, const float* __restrict__ WA,
    const float* __restrict__ WB, float* __restrict__ Aout,
    float* __restrict__ Bout)
{
  __shared__ float Xs[32][68];   // transposed [k][row]
  __shared__ float WAs[32][32];
  __shared__ float WBs[32][32];
  const int tid = threadIdx.x;
  const int tx = tid & 31;        // output col 0..31
  const int ty = tid >> 5;        // 0..7 -> rows ty*8..ty*8+7
  const int m0 = blockIdx.x * 64;
  float accA[8] = {}, accB[8] = {};
  const int wr = tid >> 3;            // 0..31
  const int wc = (tid & 7) << 2;      // 0,4,..,28
  for (int k0 = 0; k0 < 2048; k0 += 32) {
    __syncthreads();
    #pragma unroll
    for (int s = 0; s < 2; ++s) {
      int idx = tid + s * 256;         // 0..511
      int r = idx >> 3, k4 = (idx & 7) << 2;
      float4 v = *(const float4*)(x + (size_t)(m0 + r) * 2048 + k0 + k4);
      Xs[k4 + 0][r] = v.x; Xs[k4 + 1][r] = v.y;
      Xs[k4 + 2][r] = v.z; Xs[k4 + 3][r] = v.w;
    }
    *(float4*)&WAs[wr][wc] = *(const float4*)(WA + (size_t)(k0 + wr) * 32 + wc);
    *(float4*)&WBs[wr][wc] = *(const float4*)(WB + (size_t)(k0 + wr) * 32 + wc);
    __syncthreads();
    #pragma unroll 4
    for (int k = 0; k < 32; ++k) {
      float wa = WAs[k][tx];
      float wb = WBs[k][tx];
      float4 x0 = *(const float4*)&Xs[k][ty * 8];
      float4 x1 = *(const float4*)&Xs[k][ty * 8 + 4];
      float xa[8] = {x0.x, x0.y, x0.z, x0.w, x1.x, x1.y, x1.z, x1.w};
      #pragma unroll
      for (int r = 0; r < 8; ++r) {
        accA[r] = fmaf(xa[r], wa, accA[r]);
        accB[r] = fmaf(xa[r], wb, accB[r]);
      }
    }
  }
  #pragma unroll
  for (int r = 0; r < 8; ++r) {
    Aout[(size_t)(m0 + ty * 8 + r) * 32 + tx] = accA[r];
    Bout[(size_t)(m0 + ty * 8 + r) * 32 + tx] = accB[r];
  }
}

// In-place RoPE on Q [T][2048] (16 heads) and K [T][512] (4 heads).
// idx -> (t, hh, d); hh<16 => Q head hh, else K head hh-16. Pairs (d, d+64).
__global__ __launch_bounds__(256) void rope_kernel(float* __restrict__ Q,
                                                   float* __restrict__ K)
{
  int idx = blockIdx.x * 256 + threadIdx.x;   // < 2048*20*64
  int d  = idx & 63;
  int hh = (idx >> 6) % 20;
  int t  = idx / (20 * 64);
  float* base;
  if (hh < 16) base = Q + (size_t)t * 2048 + hh * 128 + d;
  else         base = K + (size_t)t * 512 + (hh - 16) * 128 + d;
  // inv_freq = 10000^(-d/64) = exp(-d * ln(10000)/64)
  float inv = expf((float)d * -0.14391156831212789f);
  float ang = (float)t * inv;
  float sn, cs;
  sincosf(ang, &sn, &cs);
  float x1 = base[0], x2 = base[64];
  base[0]  = x1 * cs - x2 * sn;
  base[64] = x2 * cs + x1 * sn;
}

// ---------------------------------------------------------------------------
// Flash-style causal attention with fused bias.
// grid (32, 16): blockIdx.y = head, qt = 31 - blockIdx.x (heavy blocks first).
// Block: 256 threads (tx=tid&15 col group, ty=tid>>4 row group), 64 q-rows,
// 64-wide KV tiles. bias = -pol*delta/4096 - gamma*delta
//                        + gate*sigmoid(dot32(A[i],B[j])), causal mask.
// ---------------------------------------------------------------------------
__global__ __launch_bounds__(256) void attn_kernel(
    const float* __restrict__ Q, const float* __restrict__ K,
    const float* __restrict__ V, const float* __restrict__ Abuf,
    const float* __restrict__ Bbuf, const float* __restrict__ pol_dir,
    const float* __restrict__ pol_gate, const float* __restrict__ gtp_gamma,
    float* __restrict__ O)
{
  __shared__ float Qs[128][68];  // transposed [k][row]
  __shared__ float Ks[128][68];  // transposed [k][col]
  __shared__ float Vs[64][128];  // row-major [j][d]
  __shared__ float As[32][68];   // transposed [k][row]
  __shared__ float Bs[32][68];   // transposed [k][col]
  __shared__ float Ps[64][68];   // transposed [j][row]

  const int tid = threadIdx.x;
  const int tx = tid & 15, ty = tid >> 4;
  const int h  = blockIdx.y;
  const int qt = (int)gridDim.x - 1 - (int)blockIdx.x;
  const int q0 = qt * 64;
  const int kvh = h >> 2;

  float pol   = fminf(fmaxf(pol_dir[h], -1.f), 1.f);
  float gamma = fmaxf(log1pf(expf(gtp_gamma[h])), 1e-6f);
  float gate  = 1.f / (1.f + expf(-pol_gate[h]));
  const float sc = 0.08838834764831845f;  // 1/sqrt(128)

  // Stage Q tile (transposed) and A tile (transposed) once.
  for (int i = tid; i < 64 * 32; i += 256) {
    int r = i >> 5, k4 = (i & 31) << 2;
    float4 v = *(const float4*)(Q + (size_t)(q0 + r) * 2048 + h * 128 + k4);
    Qs[k4 + 0][r] = v.x; Qs[k4 + 1][r] = v.y;
    Qs[k4 + 2][r] = v.z; Qs[k4 + 3][r] = v.w;
  }
  for (int i = tid; i < 64 * 8; i += 256) {
    int r = i >> 3, k4 = (i & 7) << 2;
    float4 v = *(const float4*)(Abuf + (size_t)(q0 + r) * 32 + k4);
    As[k4 + 0][r] = v.x; As[k4 + 1][r] = v.y;
    As[k4 + 2][r] = v.z; As[k4 + 3][r] = v.w;
  }

  float m[4], l[4], acc[4][8];
  #pragma unroll
  for (int a = 0; a < 4; ++a) {
    m[a] = -INFINITY; l[a] = 0.f;
    #pragma unroll
    for (int d = 0; d < 8; ++d) acc[a][d] = 0.f;
  }

  for (int jt = 0; jt <= qt; ++jt) {
    const int j0 = jt * 64;
    __syncthreads();  // previous PV reads done before restage (also covers Q staging)
    for (int i = tid; i < 64 * 32; i += 256) {
      int r = i >> 5, k4 = (i & 31) << 2;
      float4 kv = *(const float4*)(K + (size_t)(j0 + r) * 512 + kvh * 128 + k4);
      Ks[k4 + 0][r] = kv.x; Ks[k4 + 1][r] = kv.y;
      Ks[k4 + 2][r] = kv.z; Ks[k4 + 3][r] = kv.w;
      float4 vv = *(const float4*)(V + (size_t)(j0 + r) * 512 + kvh * 128 + k4);
      *(float4*)&Vs[r][k4] = vv;
    }
    for (int i = tid; i < 64 * 8; i += 256) {
      int r = i >> 3, k4 = (i & 7) << 2;
      float4 v = *(const float4*)(Bbuf + (size_t)(j0 + r) * 32 + k4);
      Bs[k4 + 0][r] = v.x; Bs[k4 + 1][r] = v.y;
      Bs[k4 + 2][r] = v.z; Bs[k4 + 3][r] = v.w;
    }
    __syncthreads();

    // S = Q.K^T  (4x4 per thread)
    float s[4][4] = {};
    #pragma unroll 4
    for (int k = 0; k < 128; ++k) {
      float4 qv = *(const float4*)&Qs[k][ty * 4];
      float4 kv = *(const float4*)&Ks[k][tx * 4];
      float qa[4] = {qv.x, qv.y, qv.z, qv.w};
      float ka[4] = {kv.x, kv.y, kv.z, kv.w};
      #pragma unroll
      for (int a = 0; a < 4; ++a)
        #pragma unroll
        for (int b = 0; b < 4; ++b)
          s[a][b] = fmaf(qa[a], ka[b], s[a][b]);
    }
    // md = A.B^T (rank-32 bias dot)
    float md[4][4] = {};
    #pragma unroll 4
    for (int k = 0; k < 32; ++k) {
      float4 av = *(const float4*)&As[k][ty * 4];
      float4 bv = *(const float4*)&Bs[k][tx * 4];
      float aa[4] = {av.x, av.y, av.z, av.w};
      float bb[4] = {bv.x, bv.y, bv.z, bv.w};
      #pragma unroll
      for (int a = 0; a < 4; ++a)
        #pragma unroll
        for (int b = 0; b < 4; ++b)
          md[a][b] = fmaf(aa[a], bb[b], md[a][b]);
    }
    // combine: scale + bias + causal mask
    #pragma unroll
    for (int a = 0; a < 4; ++a) {
      int qi = q0 + ty * 4 + a;
      #pragma unroll
      for (int b = 0; b < 4; ++b) {
        int kj = j0 + tx * 4 + b;
        float delta = (float)(qi - kj);
        float mm = 1.f / (1.f + expf(-md[a][b]));
        float bias = -pol * delta * (1.f / 4096.f) - gamma * delta + gate * mm;
        float val = s[a][b] * sc + bias;
        if (kj > qi) val = -INFINITY;
        s[a][b] = val;
      }
    }
    // online softmax: row reductions across the 16 tx lanes
    #pragma unroll
    for (int a = 0; a < 4; ++a) {
      float mx = fmaxf(fmaxf(s[a][0], s[a][1]), fmaxf(s[a][2], s[a][3]));
      #pragma unroll
      for (int o = 1; o < 16; o <<= 1) mx = fmaxf(mx, __shfl_xor(mx, o));
      float mn = fmaxf(m[a], mx);
      float es = expf(m[a] - mn);   // first tile: exp(-inf)=0
      float rs = 0.f;
      #pragma unroll
      for (int b = 0; b < 4; ++b) {
        float p = expf(s[a][b] - mn);  // masked -> exp(-inf)=0
        s[a][b] = p;
        rs += p;
      }
      #pragma unroll
      for (int o = 1; o < 16; o <<= 1) rs += __shfl_xor(rs, o);
      l[a] = l[a] * es + rs;
      m[a] = mn;
      #pragma unroll
      for (int d = 0; d < 8; ++d) acc[a][d] *= es;
    }
    // write P transposed: Ps[col][row]
    #pragma unroll
    for (int a = 0; a < 4; ++a)
      #pragma unroll
      for (int b = 0; b < 4; ++b)
        Ps[tx * 4 + b][ty * 4 + a] = s[a][b];
    __syncthreads();
    // PV: acc[row][d] += P[row][j] * V[j][d], d = tx*8..tx*8+7
    #pragma unroll 2
    for (int j = 0; j < 64; ++j) {
      float4 pv = *(const float4*)&Ps[j][ty * 4];
      float4 v0 = *(const float4*)&Vs[j][tx * 8];
      float4 v1 = *(const float4*)&Vs[j][tx * 8 + 4];
      float pa[4] = {pv.x, pv.y, pv.z, pv.w};
      #pragma unroll
      for (int a = 0; a < 4; ++a) {
        acc[a][0] = fmaf(pa[a], v0.x, acc[a][0]);
        acc[a][1] = fmaf(pa[a], v0.y, acc[a][1]);
        acc[a][2] = fmaf(pa[a], v0.z, acc[a][2]);
        acc[a][3] = fmaf(pa[a], v0.w, acc[a][3]);
        acc[a][4] = fmaf(pa[a], v1.x, acc[a][4]);
        acc[a][5] = fmaf(pa[a], v1.y, acc[a][5]);
        acc[a][6] = fmaf(pa[a], v1.z, acc[a][6]);
        acc[a][7] = fmaf(pa[a], v1.w, acc[a][7]);
      }
    }
  }
  // epilogue: normalize and store to AO [T][2048]
  #pragma unroll
  for (int a = 0; a < 4; ++a) {
    float inv = 1.f / l[a];
    float4 o0 = {acc[a][0] * inv, acc[a][1] * inv, acc[a][2] * inv, acc[a][3] * inv};
    float4 o1 = {acc[a][4] * inv, acc[a][5] * inv, acc[a][6] * inv, acc[a][7] * inv};
    float* orow = O + (size_t)(q0 + ty * 4 + a) * 2048 + h * 128 + tx * 8;
    *(float4*)orow = o0;
    *(float4*)(orow + 4) = o1;
  }
}

extern "C" void kernel_launch(void* const* d_in, const int* in_sizes, int n_in,
                              void* d_out, int out_size, void* d_ws, size_t ws_size,
                              hipStream_t stream) {
  const float* x         = (const float*)d_in[0];
  const float* Wq        = (const float*)d_in[1];
  const float* Wk        = (const float*)d_in[2];
  const float* Wv        = (const float*)d_in[3];
  const float* Wo        = (const float*)d_in[4];
  const float* pol_dir   = (const float*)d_in[5];
  const float* pol_WA    = (const float*)d_in[6];
  const float* pol_WB    = (const float*)d_in[7];
  const float* pol_gate  = (const float*)d_in[8];
  const float* gtp_gamma = (const float*)d_in[9];
  float* out = (float*)d_out;

  float* ws = (float*)d_ws;
  float* Qb = ws;                 // 2048*2048   = 4194304 floats
  float* Kb = Qb + 4194304;       // 2048*512    = 1048576
  float* Vb = Kb + 1048576;       // 2048*512    = 1048576
  float* Ab = Vb + 1048576;       // 2048*32     = 65536
  float* Bb = Ab + 65536;         // 2048*32     = 65536
  float* AO = Bb + 65536;         // 2048*2048   = 4194304
  // total: 10,616,832 floats = 42.5 MB of d_ws

  gemm_qkv_kernel<<<dim3(24, 16), 256, 0, stream>>>(x, Wq, Wk, Wv, Qb, Kb, Vb);
  gemm_ab_kernel<<<32, 256, 0, stream>>>(x, pol_WA, pol_WB, Ab, Bb);
  rope_kernel<<<10240, 256, 0, stream>>>(Qb, Kb);
  attn_kernel<<<dim3(32, 16), 256, 0, stream>>>(Qb, Kb, Vb, Ab, Bb,
                                                pol_dir, pol_gate, gtp_gamma, AO);
  gemm_out_kernel<<<dim3(16, 16), 256, 0, stream>>>(AO, Wo, out);
}

// Round 2
// 398.586 us; speedup vs baseline: 4.6180x; 4.6180x over previous
//
#include <hip/hip_runtime.h>
#include <math.h>

// ---------------------------------------------------------------------------
// Types / helpers
// ---------------------------------------------------------------------------
typedef short bf16x8 __attribute__((ext_vector_type(8)));   // 8 bf16 (4 VGPRs)
typedef float f32x4  __attribute__((ext_vector_type(4)));

#define MFMA16 __builtin_amdgcn_mfma_f32_16x16x32_bf16

static __device__ __forceinline__ short f2bf(float f) {
  union { float f; unsigned u; } x; x.f = f;
  unsigned r = (x.u + 0x7FFFu + ((x.u >> 16) & 1u)) >> 16;  // RTNE
  return (short)r;
}
static __device__ __forceinline__ unsigned packbf(float a, float b) {
  return (unsigned)(unsigned short)f2bf(a) | ((unsigned)(unsigned short)f2bf(b) << 16);
}
static __device__ __forceinline__ float bf2f(short s) {
  union { unsigned u; float f; } x; x.u = ((unsigned)(unsigned short)s) << 16;
  return x.f;
}
static __device__ __forceinline__ void gload_lds16(const void* g, void* l) {
  __builtin_amdgcn_global_load_lds((const __attribute__((address_space(1))) void*)g,
                                   (__attribute__((address_space(3))) void*)l, 16, 0, 0);
}

// ---------------------------------------------------------------------------
// fp32 -> bf16 elementwise convert (4 elems/thread)
// ---------------------------------------------------------------------------
__global__ __launch_bounds__(256) void convert_f32_bf16(
    const float* __restrict__ in, short* __restrict__ out, int n4)
{
  int i = blockIdx.x * 256 + threadIdx.x;
  if (i >= n4) return;
  float4 v = ((const float4*)in)[i];
  short4 o;
  o.x = f2bf(v.x); o.y = f2bf(v.y); o.z = f2bf(v.z); o.w = f2bf(v.w);
  ((short4*)out)[i] = o;
}

// ---------------------------------------------------------------------------
// fp32 [K][N] -> bf16 [N][K] transpose-convert, 32x32 tiles
// ---------------------------------------------------------------------------
__global__ __launch_bounds__(256) void transpose_f32_bf16(
    const float* __restrict__ in, short* __restrict__ out, int K, int N)
{
  __shared__ float t[32][33];
  int n0 = blockIdx.x * 32, k0 = blockIdx.y * 32;
  int tx = threadIdx.x & 31, ty = threadIdx.x >> 5;
  #pragma unroll
  for (int i = 0; i < 4; ++i)
    t[ty + 8 * i][tx] = in[(size_t)(k0 + ty + 8 * i) * N + n0 + tx];
  __syncthreads();
  #pragma unroll
  for (int i = 0; i < 4; ++i)
    out[(size_t)(n0 + ty + 8 * i) * K + k0 + tx] = f2bf(t[tx][ty + 8 * i]);
}

// ---------------------------------------------------------------------------
// bf16 MFMA GEMM core: C128x128 tile, BK=32, A [M][K] row-major bf16,
// Bt [N][K] row-major bf16 (i.e. B transposed). 256 threads, 4 waves 2x2,
// each wave 4x4 16x16 frags. global_load_lds staging (linear LDS).
// ---------------------------------------------------------------------------
__device__ __forceinline__ void gemm128_core(
    const short* __restrict__ A, const short* __restrict__ Bt,
    int m0, int n0, int Kd, short* Asm, short* Bsm, f32x4 acc[4][4])
{
  const int tid = threadIdx.x;
  const int lane = tid & 63, w = tid >> 6;
  const int lr = lane & 15, g4 = lane >> 4;
  const int wm = w >> 1, wn = w & 1;

  for (int k0 = 0; k0 < Kd; k0 += 32) {
    #pragma unroll
    for (int s = 0; s < 2; ++s) {
      int c = (s * 4 + w) * 64 + lane;   // 0..511
      int row = c >> 2, q = c & 3;       // row 0..127, 16B chunk q
      gload_lds16(A  + (size_t)(m0 + row) * Kd + k0 + q * 8,
                  Asm + (size_t)(s * 4 + w) * 64 * 8);
      gload_lds16(Bt + (size_t)(n0 + row) * Kd + k0 + q * 8,
                  Bsm + (size_t)(s * 4 + w) * 64 * 8);
    }
    __syncthreads();
    bf16x8 af[4], bff[4];
    #pragma unroll
    for (int mi = 0; mi < 4; ++mi)
      af[mi] = *(const bf16x8*)(Asm + (wm * 64 + mi * 16 + lr) * 32 + g4 * 8);
    #pragma unroll
    for (int ni = 0; ni < 4; ++ni)
      bff[ni] = *(const bf16x8*)(Bsm + (wn * 64 + ni * 16 + lr) * 32 + g4 * 8);
    #pragma unroll
    for (int mi = 0; mi < 4; ++mi)
      #pragma unroll
      for (int ni = 0; ni < 4; ++ni)
        acc[mi][ni] = MFMA16(af[mi], bff[ni], acc[mi][ni], 0, 0, 0);
    __syncthreads();
  }
}

// Fused QKV projection. grid (24, 16). bx<16: Q, bx<20: K, else V (transposed out).
__global__ __launch_bounds__(256, 3) void gemm_qkv_kernel(
    const short* __restrict__ xb, const short* __restrict__ Wqt,
    const short* __restrict__ Wkt, const short* __restrict__ Wvt,
    short* __restrict__ Qb, short* __restrict__ Kb, short* __restrict__ Vtb)
{
  __shared__ __align__(16) short Asm[128 * 32];
  __shared__ __align__(16) short Bsm[128 * 32];
  f32x4 acc[4][4];
  #pragma unroll
  for (int i = 0; i < 4; ++i)
    #pragma unroll
    for (int j = 0; j < 4; ++j) acc[i][j] = (f32x4){0.f, 0.f, 0.f, 0.f};

  const int bx = blockIdx.x, by = blockIdx.y;
  const short* Bt; int mode, nl0;
  if (bx < 16)      { Bt = Wqt; nl0 = bx * 128;        mode = 0; }
  else if (bx < 20) { Bt = Wkt; nl0 = (bx - 16) * 128; mode = 1; }
  else              { Bt = Wvt; nl0 = (bx - 20) * 128; mode = 2; }

  gemm128_core(xb, Bt, by * 128, nl0, 2048, Asm, Bsm, acc);

  const int tid = threadIdx.x, lane = tid & 63, w = tid >> 6;
  const int lr = lane & 15, g4 = lane >> 4, wm = w >> 1, wn = w & 1;
  #pragma unroll
  for (int mi = 0; mi < 4; ++mi) {
    #pragma unroll
    for (int ni = 0; ni < 4; ++ni) {
      int mb = by * 128 + wm * 64 + mi * 16 + g4 * 4;
      int nc = nl0 + wn * 64 + ni * 16 + lr;
      if (mode == 0) {
        #pragma unroll
        for (int r = 0; r < 4; ++r)
          Qb[(size_t)(mb + r) * 2048 + nc] = f2bf(acc[mi][ni][r]);
      } else if (mode == 1) {
        #pragma unroll
        for (int r = 0; r < 4; ++r)
          Kb[(size_t)(mb + r) * 512 + nc] = f2bf(acc[mi][ni][r]);
      } else {
        uint2 uu;
        uu.x = packbf(acc[mi][ni][0], acc[mi][ni][1]);
        uu.y = packbf(acc[mi][ni][2], acc[mi][ni][3]);
        *(uint2*)(Vtb + (size_t)nc * 2048 + mb) = uu;   // V^T [512][2048]
      }
    }
  }
}

// Output projection: out = AO(bf16) @ Wo -> fp32. grid (16,16).
__global__ __launch_bounds__(256, 3) void gemm_out_kernel(
    const short* __restrict__ AO, const short* __restrict__ Wot,
    float* __restrict__ out)
{
  __shared__ __align__(16) short Asm[128 * 32];
  __shared__ __align__(16) short Bsm[128 * 32];
  f32x4 acc[4][4];
  #pragma unroll
  for (int i = 0; i < 4; ++i)
    #pragma unroll
    for (int j = 0; j < 4; ++j) acc[i][j] = (f32x4){0.f, 0.f, 0.f, 0.f};

  gemm128_core(AO, Wot, blockIdx.y * 128, blockIdx.x * 128, 2048, Asm, Bsm, acc);

  const int tid = threadIdx.x, lane = tid & 63, w = tid >> 6;
  const int lr = lane & 15, g4 = lane >> 4, wm = w >> 1, wn = w & 1;
  #pragma unroll
  for (int mi = 0; mi < 4; ++mi)
    #pragma unroll
    for (int ni = 0; ni < 4; ++ni) {
      int mb = blockIdx.y * 128 + wm * 64 + mi * 16 + g4 * 4;
      int nc = blockIdx.x * 128 + wn * 64 + ni * 16 + lr;
      #pragma unroll
      for (int r = 0; r < 4; ++r)
        out[(size_t)(mb + r) * 2048 + nc] = acc[mi][ni][r];
    }
}

// ---------------------------------------------------------------------------
// Low-rank projections A = x@WA, Bm = x@WB (fp32 compute, bf16 store).
// ---------------------------------------------------------------------------
__global__ __launch_bounds__(256) void gemm_ab_kernel(
    const float* __restrict__ x, const float* __restrict__ WA,
    const float* __restrict__ WB, short* __restrict__ Aout,
    short* __restrict__ Bout)
{
  __shared__ __align__(16) float Xs[32][68];
  __shared__ __align__(16) float WAs[32][32];
  __shared__ __align__(16) float WBs[32][32];
  const int tid = threadIdx.x;
  const int tx = tid & 31;
  const int ty = tid >> 5;
  const int m0 = blockIdx.x * 64;
  float accA[8] = {}, accB[8] = {};
  const int wr = tid >> 3;
  const int wc = (tid & 7) << 2;
  for (int k0 = 0; k0 < 2048; k0 += 32) {
    __syncthreads();
    #pragma unroll
    for (int s = 0; s < 2; ++s) {
      int idx = tid + s * 256;
      int r = idx >> 3, k4 = (idx & 7) << 2;
      float4 v = *(const float4*)(x + (size_t)(m0 + r) * 2048 + k0 + k4);
      Xs[k4 + 0][r] = v.x; Xs[k4 + 1][r] = v.y;
      Xs[k4 + 2][r] = v.z; Xs[k4 + 3][r] = v.w;
    }
    *(float4*)&WAs[wr][wc] = *(const float4*)(WA + (size_t)(k0 + wr) * 32 + wc);
    *(float4*)&WBs[wr][wc] = *(const float4*)(WB + (size_t)(k0 + wr) * 32 + wc);
    __syncthreads();
    #pragma unroll 4
    for (int k = 0; k < 32; ++k) {
      float wa = WAs[k][tx];
      float wb = WBs[k][tx];
      float4 x0 = *(const float4*)&Xs[k][ty * 8];
      float4 x1 = *(const float4*)&Xs[k][ty * 8 + 4];
      float xa[8] = {x0.x, x0.y, x0.z, x0.w, x1.x, x1.y, x1.z, x1.w};
      #pragma unroll
      for (int r = 0; r < 8; ++r) {
        accA[r] = fmaf(xa[r], wa, accA[r]);
        accB[r] = fmaf(xa[r], wb, accB[r]);
      }
    }
  }
  #pragma unroll
  for (int r = 0; r < 8; ++r) {
    Aout[(size_t)(m0 + ty * 8 + r) * 32 + tx] = f2bf(accA[r]);
    Bout[(size_t)(m0 + ty * 8 + r) * 32 + tx] = f2bf(accB[r]);
  }
}

// ---------------------------------------------------------------------------
// In-place RoPE on bf16 Q [T][2048], K [T][512]. Pair (d, d+64) per head.
// ---------------------------------------------------------------------------
__global__ __launch_bounds__(256) void rope_kernel(short* __restrict__ Q,
                                                   short* __restrict__ K)
{
  int idx = blockIdx.x * 256 + threadIdx.x;   // < 2048*20*64
  int d  = idx & 63;
  int hh = (idx >> 6) % 20;
  int t  = idx / (20 * 64);
  short* base = (hh < 16) ? Q + (size_t)t * 2048 + hh * 128 + d
                          : K + (size_t)t * 512 + (hh - 16) * 128 + d;
  float inv = __expf((float)d * -0.14391156831212789f);  // 10000^(-d/64)
  float ang = (float)t * inv;
  float sn, cs;
  __sincosf(ang, &sn, &cs);
  float x1 = bf2f(base[0]), x2 = bf2f(base[64]);
  base[0]  = f2bf(x1 * cs - x2 * sn);
  base[64] = f2bf(x2 * cs + x1 * sn);
}

// ---------------------------------------------------------------------------
// Flash attention, bf16 MFMA. grid (32,16): by=head, qt = 31-bx.
// 4 waves, 64 q-rows/block (16/wave), KV tile 64. Swapped QK^T: lane holds
// S^T values for q-row (lane&15), kv = cb*16 + (lane>>4)*4 + r.
// XOR swizzle ((row&7)<<4) on all 128/256-B-row LDS tiles.
// ---------------------------------------------------------------------------
__global__ __launch_bounds__(256, 2) void attn_kernel(
    const short* __restrict__ Qg, const short* __restrict__ Kg,
    const short* __restrict__ Vtg, const short* __restrict__ Ag,
    const short* __restrict__ Bg, const float* __restrict__ pol_dir,
    const float* __restrict__ pol_gate, const float* __restrict__ gtp_gamma,
    short* __restrict__ AO)
{
  __shared__ __align__(16) char Qs[16384];   // [64 rows][128 bf16] swz
  __shared__ __align__(16) char Ks[16384];   // [64 rows][128 bf16] swz
  __shared__ __align__(16) char Vs[16384];   // [128 rows(d)][64 bf16(kv)] swz
  __shared__ __align__(16) char As_[5120];   // [64 rows][32 bf16] pitch 80B
  __shared__ __align__(16) char Bs_[5120];
  __shared__ __align__(16) char Ps[8192];    // per wave [16 rows][64 bf16] swz

  const int tid = threadIdx.x;
  const int lane = tid & 63, w = tid >> 6;
  const int lr = lane & 15, g4 = lane >> 4;
  const int h = blockIdx.y;
  const int qt = 31 - (int)blockIdx.x;
  const int q0 = qt * 64;
  const int kvh = h >> 2;

  float pol   = fminf(fmaxf(pol_dir[h], -1.f), 1.f);
  float gamma = fmaxf(log1pf(__expf(gtp_gamma[h])), 1e-6f);
  float gate  = 1.f / (1.f + __expf(-pol_gate[h]));
  const float sc = 0.08838834764831845f;     // 1/sqrt(128)
  const f32x4 z4 = {0.f, 0.f, 0.f, 0.f};

  // stage Q tile (swizzled) + A tile (pitch 80, no swizzle needed)
  #pragma unroll
  for (int s = 0; s < 4; ++s) {
    int c = tid + s * 256;                  // 0..1023
    int row = c >> 4, sl = c & 15;
    int4 v = *(const int4*)(Qg + (size_t)(q0 + row) * 2048 + h * 128 + sl * 8);
    *(int4*)(Qs + row * 256 + ((sl * 16) ^ ((row & 7) << 4))) = v;
  }
  {
    int row = tid >> 2, sl = tid & 3;
    int4 v = *(const int4*)(Ag + (size_t)(q0 + row) * 32 + sl * 8);
    *(int4*)(As_ + row * 80 + sl * 16) = v;
  }
  __syncthreads();

  // hoist Q frags (q-row = w*16+lr) and A frag
  bf16x8 qf[4];
  #pragma unroll
  for (int kk = 0; kk < 4; ++kk)
    qf[kk] = *(const bf16x8*)(Qs + (w * 16 + lr) * 256 +
                              ((kk * 64 + g4 * 16) ^ ((lr & 7) << 4)));
  bf16x8 afr = *(const bf16x8*)(As_ + (w * 16 + lr) * 80 + g4 * 16);

  f32x4 acc_o[8];
  #pragma unroll
  for (int i = 0; i < 8; ++i) acc_o[i] = z4;
  float m_st = -INFINITY, l_st = 0.f;
  char* Pw = Ps + w * 2048;

  for (int jt = 0; jt <= qt; ++jt) {
    const int j0 = jt * 64;
    __syncthreads();
    #pragma unroll
    for (int s = 0; s < 4; ++s) {
      int c = tid + s * 256;
      int row = c >> 4, sl = c & 15;
      int4 v = *(const int4*)(Kg + (size_t)(j0 + row) * 512 + kvh * 128 + sl * 8);
      *(int4*)(Ks + row * 256 + ((sl * 16) ^ ((row & 7) << 4))) = v;
    }
    #pragma unroll
    for (int s = 0; s < 4; ++s) {
      int c = tid + s * 256;
      int row = c >> 3, sl = c & 7;       // d-row, kv chunk
      int4 v = *(const int4*)(Vtg + (size_t)(kvh * 128 + row) * 2048 + j0 + sl * 8);
      *(int4*)(Vs + row * 128 + ((sl * 16) ^ ((row & 7) << 4))) = v;
    }
    {
      int row = tid >> 2, sl = tid & 3;
      int4 v = *(const int4*)(Bg + (size_t)(j0 + row) * 32 + sl * 8);
      *(int4*)(Bs_ + row * 80 + sl * 16) = v;
    }
    __syncthreads();

    // S^T = K . Q^T and md = Bm . A^T
    f32x4 acc_s[4], md[4];
    #pragma unroll
    for (int cb = 0; cb < 4; ++cb) {
      acc_s[cb] = z4;
      #pragma unroll
      for (int kk = 0; kk < 4; ++kk) {
        bf16x8 kf = *(const bf16x8*)(Ks + (cb * 16 + lr) * 256 +
                                     ((kk * 64 + g4 * 16) ^ ((lr & 7) << 4)));
        acc_s[cb] = MFMA16(kf, qf[kk], acc_s[cb], 0, 0, 0);
      }
      bf16x8 bmf = *(const bf16x8*)(Bs_ + (cb * 16 + lr) * 80 + g4 * 16);
      md[cb] = MFMA16(bmf, afr, z4, 0, 0, 0);
    }

    // bias + causal mask + online softmax (row = q = lr; 4 lanes share row)
    const int qi = q0 + w * 16 + lr;
    float mx = -INFINITY;
    #pragma unroll
    for (int cb = 0; cb < 4; ++cb)
      #pragma unroll
      for (int r = 0; r < 4; ++r) {
        int kj = j0 + cb * 16 + g4 * 4 + r;
        float sv;
        if (kj > qi) sv = -INFINITY;
        else {
          float delta = (float)(qi - kj);
          float sig = 1.f / (1.f + __expf(-md[cb][r]));
          sv = acc_s[cb][r] * sc - pol * delta * (1.f / 4096.f) - gamma * delta
               + gate * sig;
        }
        acc_s[cb][r] = sv;
        mx = fmaxf(mx, sv);
      }
    mx = fmaxf(mx, __shfl_xor(mx, 16));
    mx = fmaxf(mx, __shfl_xor(mx, 32));
    float mn = fmaxf(m_st, mx);
    float es = __expf(m_st - mn);
    float rs = 0.f;
    #pragma unroll
    for (int cb = 0; cb < 4; ++cb)
      #pragma unroll
      for (int r = 0; r < 4; ++r) {
        float p = __expf(acc_s[cb][r] - mn);
        acc_s[cb][r] = p;
        rs += p;
      }
    rs += __shfl_xor(rs, 16);
    rs += __shfl_xor(rs, 32);
    l_st = l_st * es + rs;
    m_st = mn;
    float es4[4];
    #pragma unroll
    for (int r = 0; r < 4; ++r) es4[r] = __shfl(es, g4 * 4 + r, 64);
    #pragma unroll
    for (int db = 0; db < 8; ++db)
      #pragma unroll
      for (int r = 0; r < 4; ++r) acc_o[db][r] *= es4[r];

    // P -> LDS (bf16, swizzled), then PV
    #pragma unroll
    for (int cb = 0; cb < 4; ++cb) {
      uint2 uu;
      uu.x = packbf(acc_s[cb][0], acc_s[cb][1]);
      uu.y = packbf(acc_s[cb][2], acc_s[cb][3]);
      *(uint2*)(Pw + lr * 128 + ((cb * 32 + g4 * 8) ^ ((lr & 7) << 4))) = uu;
    }
    asm volatile("s_waitcnt lgkmcnt(0)" ::: "memory");
    __builtin_amdgcn_sched_barrier(0);
    #pragma unroll
    for (int kk = 0; kk < 2; ++kk) {
      bf16x8 pf = *(const bf16x8*)(Pw + lr * 128 +
                                   ((kk * 64 + g4 * 16) ^ ((lr & 7) << 4)));
      #pragma unroll
      for (int db = 0; db < 8; ++db) {
        bf16x8 vf = *(const bf16x8*)(Vs + (db * 16 + lr) * 128 +
                                     ((kk * 64 + g4 * 16) ^ ((lr & 7) << 4)));
        acc_o[db] = MFMA16(pf, vf, acc_o[db], 0, 0, 0);
      }
    }
  }

  // epilogue: normalize, store bf16 AO. acc rows q = g4*4+r, col d = db*16+lr.
  float lrcp[4];
  #pragma unroll
  for (int r = 0; r < 4; ++r) lrcp[r] = 1.f / __shfl(l_st, g4 * 4 + r, 64);
  #pragma unroll
  for (int db = 0; db < 8; ++db)
    #pragma unroll
    for (int r = 0; r < 4; ++r)
      AO[(size_t)(q0 + w * 16 + g4 * 4 + r) * 2048 + h * 128 + db * 16 + lr] =
          f2bf(acc_o[db][r] * lrcp[r]);
}

// ---------------------------------------------------------------------------
// Launch
// ---------------------------------------------------------------------------
extern "C" void kernel_launch(void* const* d_in, const int* in_sizes, int n_in,
                              void* d_out, int out_size, void* d_ws, size_t ws_size,
                              hipStream_t stream) {
  const float* x         = (const float*)d_in[0];
  const float* Wq        = (const float*)d_in[1];
  const float* Wk        = (const float*)d_in[2];
  const float* Wv        = (const float*)d_in[3];
  const float* Wo        = (const float*)d_in[4];
  const float* pol_dir   = (const float*)d_in[5];
  const float* pol_WA    = (const float*)d_in[6];
  const float* pol_WB    = (const float*)d_in[7];
  const float* pol_gate  = (const float*)d_in[8];
  const float* gtp_gamma = (const float*)d_in[9];
  float* out = (float*)d_out;

  char* ws = (char*)d_ws;
  short* Qb  = (short*)(ws);                    // 2048x2048 bf16 = 8 MB
  short* Kb  = (short*)(ws + 8388608);          // 2048x512  bf16 = 2 MB
  short* Vtb = (short*)(ws + 10485760);         // 512x2048  bf16 = 2 MB (V^T)
  short* Ab  = (short*)(ws + 12582912);         // 2048x32   bf16 = 128 KB
  short* Bb  = (short*)(ws + 12713984);         // 2048x32   bf16 = 128 KB
  short* xb  = (short*)(ws + 12845056);         // 8 MB (later reused as Wot)
  short* Wot = xb;                              // written after gemm_qkv done
  short* Wqt = (short*)(ws + 21233664);         // 8 MB (later reused as AO)
  short* AO  = Wqt;                             // written after gemm_qkv done
  short* Wkt = (short*)(ws + 29622272);         // 2 MB
  short* Wvt = (short*)(ws + 31719424);         // 2 MB  (total 33.8 MB)

  convert_f32_bf16<<<4096, 256, 0, stream>>>(x, xb, 1048576);
  transpose_f32_bf16<<<dim3(64, 64), 256, 0, stream>>>(Wq, Wqt, 2048, 2048);
  transpose_f32_bf16<<<dim3(16, 64), 256, 0, stream>>>(Wk, Wkt, 2048, 512);
  transpose_f32_bf16<<<dim3(16, 64), 256, 0, stream>>>(Wv, Wvt, 2048, 512);
  gemm_qkv_kernel<<<dim3(24, 16), 256, 0, stream>>>(xb, Wqt, Wkt, Wvt, Qb, Kb, Vtb);
  gemm_ab_kernel<<<32, 256, 0, stream>>>(x, pol_WA, pol_WB, Ab, Bb);
  rope_kernel<<<10240, 256, 0, stream>>>(Qb, Kb);
  transpose_f32_bf16<<<dim3(64, 64), 256, 0, stream>>>(Wo, Wot, 2048, 2048);
  attn_kernel<<<dim3(32, 16), 256, 0, stream>>>(Qb, Kb, Vtb, Ab, Bb,
                                                pol_dir, pol_gate, gtp_gamma, AO);
  gemm_out_kernel<<<dim3(16, 16), 256, 0, stream>>>(AO, Wot, out);
}

// Round 3
// 235.959 us; speedup vs baseline: 7.8009x; 1.6892x over previous
//
#include <hip/hip_runtime.h>
#include <math.h>

// ---------------------------------------------------------------------------
// Types / helpers
// ---------------------------------------------------------------------------
typedef short bf16x8 __attribute__((ext_vector_type(8)));   // 8 bf16 (4 VGPRs)
typedef float f32x4  __attribute__((ext_vector_type(4)));

#define MFMA16 __builtin_amdgcn_mfma_f32_16x16x32_bf16

static __device__ __forceinline__ short f2bf(float f) {
  union { float f; unsigned u; } x; x.f = f;
  unsigned r = (x.u + 0x7FFFu + ((x.u >> 16) & 1u)) >> 16;  // RTNE
  return (short)r;
}
static __device__ __forceinline__ unsigned packbf(float a, float b) {
  return (unsigned)(unsigned short)f2bf(a) | ((unsigned)(unsigned short)f2bf(b) << 16);
}
static __device__ __forceinline__ float bf2f(short s) {
  union { unsigned u; float f; } x; x.u = ((unsigned)(unsigned short)s) << 16;
  return x.f;
}
static __device__ __forceinline__ void gload_lds16(const void* g, void* l) {
  __builtin_amdgcn_global_load_lds((const __attribute__((address_space(1))) void*)g,
                                   (__attribute__((address_space(3))) void*)l, 16, 0, 0);
}

// ---------------------------------------------------------------------------
// fp32 -> bf16 elementwise convert (4 elems/thread)
// ---------------------------------------------------------------------------
__global__ __launch_bounds__(256) void convert_f32_bf16(
    const float* __restrict__ in, short* __restrict__ out, int n4)
{
  int i = blockIdx.x * 256 + threadIdx.x;
  if (i >= n4) return;
  float4 v = ((const float4*)in)[i];
  short4 o;
  o.x = f2bf(v.x); o.y = f2bf(v.y); o.z = f2bf(v.z); o.w = f2bf(v.w);
  ((short4*)out)[i] = o;
}

// ---------------------------------------------------------------------------
// fp32 [K][N] -> bf16 [N][K] transpose-convert, 32x32 tiles
// ---------------------------------------------------------------------------
__global__ __launch_bounds__(256) void transpose_f32_bf16(
    const float* __restrict__ in, short* __restrict__ out, int K, int N)
{
  __shared__ float t[32][33];
  int n0 = blockIdx.x * 32, k0 = blockIdx.y * 32;
  int tx = threadIdx.x & 31, ty = threadIdx.x >> 5;
  #pragma unroll
  for (int i = 0; i < 4; ++i)
    t[ty + 8 * i][tx] = in[(size_t)(k0 + ty + 8 * i) * N + n0 + tx];
  __syncthreads();
  #pragma unroll
  for (int i = 0; i < 4; ++i)
    out[(size_t)(n0 + ty + 8 * i) * K + k0 + tx] = f2bf(t[tx][ty + 8 * i]);
}

// ---------------------------------------------------------------------------
// bf16 MFMA GEMM core: C128x128 tile, BK=32, A [M][K] row-major bf16,
// Bt [N][K] row-major bf16 (i.e. B transposed). 256 threads, 4 waves 2x2,
// each wave 4x4 16x16 frags. global_load_lds staging (linear LDS).
// ---------------------------------------------------------------------------
__device__ __forceinline__ void gemm128_core(
    const short* __restrict__ A, const short* __restrict__ Bt,
    int m0, int n0, int Kd, short* Asm, short* Bsm, f32x4 acc[4][4])
{
  const int tid = threadIdx.x;
  const int lane = tid & 63, w = tid >> 6;
  const int lr = lane & 15, g4 = lane >> 4;
  const int wm = w >> 1, wn = w & 1;

  for (int k0 = 0; k0 < Kd; k0 += 32) {
    #pragma unroll
    for (int s = 0; s < 2; ++s) {
      int c = (s * 4 + w) * 64 + lane;   // 0..511
      int row = c >> 2, q = c & 3;       // row 0..127, 16B chunk q
      gload_lds16(A  + (size_t)(m0 + row) * Kd + k0 + q * 8,
                  Asm + (size_t)(s * 4 + w) * 64 * 8);
      gload_lds16(Bt + (size_t)(n0 + row) * Kd + k0 + q * 8,
                  Bsm + (size_t)(s * 4 + w) * 64 * 8);
    }
    __syncthreads();
    bf16x8 af[4], bff[4];
    #pragma unroll
    for (int mi = 0; mi < 4; ++mi)
      af[mi] = *(const bf16x8*)(Asm + (wm * 64 + mi * 16 + lr) * 32 + g4 * 8);
    #pragma unroll
    for (int ni = 0; ni < 4; ++ni)
      bff[ni] = *(const bf16x8*)(Bsm + (wn * 64 + ni * 16 + lr) * 32 + g4 * 8);
    #pragma unroll
    for (int mi = 0; mi < 4; ++mi)
      #pragma unroll
      for (int ni = 0; ni < 4; ++ni)
        acc[mi][ni] = MFMA16(af[mi], bff[ni], acc[mi][ni], 0, 0, 0);
    __syncthreads();
  }
}

// Fused QKV + low-rank AB projection. grid (25, 16).
// bx<16: Q, bx<20: K, bx<24: V (transposed out), bx==24: A|B (N=64 useful).
__global__ __launch_bounds__(256, 3) void gemm_qkv_kernel(
    const short* __restrict__ xb, const short* __restrict__ Wqt,
    const short* __restrict__ Wkt, const short* __restrict__ Wvt,
    const short* __restrict__ WABt,
    short* __restrict__ Qb, short* __restrict__ Kb, short* __restrict__ Vtb,
    short* __restrict__ Ab, short* __restrict__ Bb)
{
  __shared__ __align__(16) short Asm[128 * 32];
  __shared__ __align__(16) short Bsm[128 * 32];
  f32x4 acc[4][4];
  #pragma unroll
  for (int i = 0; i < 4; ++i)
    #pragma unroll
    for (int j = 0; j < 4; ++j) acc[i][j] = (f32x4){0.f, 0.f, 0.f, 0.f};

  const int bx = blockIdx.x, by = blockIdx.y;
  const short* Bt; int mode, nl0;
  if (bx < 16)      { Bt = Wqt;  nl0 = bx * 128;        mode = 0; }
  else if (bx < 20) { Bt = Wkt;  nl0 = (bx - 16) * 128; mode = 1; }
  else if (bx < 24) { Bt = Wvt;  nl0 = (bx - 20) * 128; mode = 2; }
  else              { Bt = WABt; nl0 = 0;               mode = 3; }

  gemm128_core(xb, Bt, by * 128, nl0, 2048, Asm, Bsm, acc);

  const int tid = threadIdx.x, lane = tid & 63, w = tid >> 6;
  const int lr = lane & 15, g4 = lane >> 4, wm = w >> 1, wn = w & 1;
  #pragma unroll
  for (int mi = 0; mi < 4; ++mi) {
    #pragma unroll
    for (int ni = 0; ni < 4; ++ni) {
      int mb = by * 128 + wm * 64 + mi * 16 + g4 * 4;
      int nc = nl0 + wn * 64 + ni * 16 + lr;
      if (mode == 0) {
        #pragma unroll
        for (int r = 0; r < 4; ++r)
          Qb[(size_t)(mb + r) * 2048 + nc] = f2bf(acc[mi][ni][r]);
      } else if (mode == 1) {
        #pragma unroll
        for (int r = 0; r < 4; ++r)
          Kb[(size_t)(mb + r) * 512 + nc] = f2bf(acc[mi][ni][r]);
      } else if (mode == 2) {
        uint2 uu;
        uu.x = packbf(acc[mi][ni][0], acc[mi][ni][1]);
        uu.y = packbf(acc[mi][ni][2], acc[mi][ni][3]);
        *(uint2*)(Vtb + (size_t)nc * 2048 + mb) = uu;   // V^T [512][2048]
      } else {
        // mode 3: cols 0-31 -> A, 32-63 -> B, wn==1 columns are dead
        if (wn == 0) {
          int col = ni * 16 + lr;   // 0..63
          #pragma unroll
          for (int r = 0; r < 4; ++r) {
            short val = f2bf(acc[mi][ni][r]);
            if (col < 32) Ab[(size_t)(mb + r) * 32 + col] = val;
            else          Bb[(size_t)(mb + r) * 32 + (col - 32)] = val;
          }
        }
      }
    }
  }
}

// Output projection: out = AO(bf16) @ Wo -> fp32. grid (16,16).
__global__ __launch_bounds__(256, 3) void gemm_out_kernel(
    const short* __restrict__ AO, const short* __restrict__ Wot,
    float* __restrict__ out)
{
  __shared__ __align__(16) short Asm[128 * 32];
  __shared__ __align__(16) short Bsm[128 * 32];
  f32x4 acc[4][4];
  #pragma unroll
  for (int i = 0; i < 4; ++i)
    #pragma unroll
    for (int j = 0; j < 4; ++j) acc[i][j] = (f32x4){0.f, 0.f, 0.f, 0.f};

  gemm128_core(AO, Wot, blockIdx.y * 128, blockIdx.x * 128, 2048, Asm, Bsm, acc);

  const int tid = threadIdx.x, lane = tid & 63, w = tid >> 6;
  const int lr = lane & 15, g4 = lane >> 4, wm = w >> 1, wn = w & 1;
  #pragma unroll
  for (int mi = 0; mi < 4; ++mi)
    #pragma unroll
    for (int ni = 0; ni < 4; ++ni) {
      int mb = blockIdx.y * 128 + wm * 64 + mi * 16 + g4 * 4;
      int nc = blockIdx.x * 128 + wn * 64 + ni * 16 + lr;
      #pragma unroll
      for (int r = 0; r < 4; ++r)
        out[(size_t)(mb + r) * 2048 + nc] = acc[mi][ni][r];
    }
}

// ---------------------------------------------------------------------------
// In-place RoPE on bf16 Q [T][2048], K [T][512]. Pair (d, d+64) per head.
// ---------------------------------------------------------------------------
__global__ __launch_bounds__(256) void rope_kernel(short* __restrict__ Q,
                                                   short* __restrict__ K)
{
  int idx = blockIdx.x * 256 + threadIdx.x;   // < 2048*20*64
  int d  = idx & 63;
  int hh = (idx >> 6) % 20;
  int t  = idx / (20 * 64);
  short* base = (hh < 16) ? Q + (size_t)t * 2048 + hh * 128 + d
                          : K + (size_t)t * 512 + (hh - 16) * 128 + d;
  float inv = __expf((float)d * -0.14391156831212789f);  // 10000^(-d/64)
  float ang = (float)t * inv;
  float sn, cs;
  __sincosf(ang, &sn, &cs);
  float x1 = bf2f(base[0]), x2 = bf2f(base[64]);
  base[0]  = f2bf(x1 * cs - x2 * sn);
  base[64] = f2bf(x2 * cs + x1 * sn);
}

// ---------------------------------------------------------------------------
// Flash attention, bf16 MFMA. grid (32,16): by=head, qt = 31-bx.
// 4 waves, 64 q-rows/block (16/wave), KV tile 64. Swapped QK^T: lane holds
// S^T values for q-row (lane&15), kv = cb*16 + (lane>>4)*4 + r.
// XOR swizzle ((row&7)<<4) on all 128/256-B-row LDS tiles.
// ---------------------------------------------------------------------------
__global__ __launch_bounds__(256, 2) void attn_kernel(
    const short* __restrict__ Qg, const short* __restrict__ Kg,
    const short* __restrict__ Vtg, const short* __restrict__ Ag,
    const short* __restrict__ Bg, const float* __restrict__ pol_dir,
    const float* __restrict__ pol_gate, const float* __restrict__ gtp_gamma,
    short* __restrict__ AO)
{
  __shared__ __align__(16) char Qs[16384];   // [64 rows][128 bf16] swz
  __shared__ __align__(16) char Ks[16384];   // [64 rows][128 bf16] swz
  __shared__ __align__(16) char Vs[16384];   // [128 rows(d)][64 bf16(kv)] swz
  __shared__ __align__(16) char As_[5120];   // [64 rows][32 bf16] pitch 80B
  __shared__ __align__(16) char Bs_[5120];
  __shared__ __align__(16) char Ps[8192];    // per wave [16 rows][64 bf16] swz

  const int tid = threadIdx.x;
  const int lane = tid & 63, w = tid >> 6;
  const int lr = lane & 15, g4 = lane >> 4;
  const int h = blockIdx.y;
  const int qt = 31 - (int)blockIdx.x;
  const int q0 = qt * 64;
  const int kvh = h >> 2;

  float pol   = fminf(fmaxf(pol_dir[h], -1.f), 1.f);
  float gamma = fmaxf(log1pf(__expf(gtp_gamma[h])), 1e-6f);
  float gate  = 1.f / (1.f + __expf(-pol_gate[h]));
  const float sc = 0.08838834764831845f;     // 1/sqrt(128)
  const f32x4 z4 = {0.f, 0.f, 0.f, 0.f};

  // stage Q tile (swizzled) + A tile (pitch 80, no swizzle needed)
  #pragma unroll
  for (int s = 0; s < 4; ++s) {
    int c = tid + s * 256;                  // 0..1023
    int row = c >> 4, sl = c & 15;
    int4 v = *(const int4*)(Qg + (size_t)(q0 + row) * 2048 + h * 128 + sl * 8);
    *(int4*)(Qs + row * 256 + ((sl * 16) ^ ((row & 7) << 4))) = v;
  }
  {
    int row = tid >> 2, sl = tid & 3;
    int4 v = *(const int4*)(Ag + (size_t)(q0 + row) * 32 + sl * 8);
    *(int4*)(As_ + row * 80 + sl * 16) = v;
  }
  __syncthreads();

  // hoist Q frags (q-row = w*16+lr) and A frag
  bf16x8 qf[4];
  #pragma unroll
  for (int kk = 0; kk < 4; ++kk)
    qf[kk] = *(const bf16x8*)(Qs + (w * 16 + lr) * 256 +
                              ((kk * 64 + g4 * 16) ^ ((lr & 7) << 4)));
  bf16x8 afr = *(const bf16x8*)(As_ + (w * 16 + lr) * 80 + g4 * 16);

  f32x4 acc_o[8];
  #pragma unroll
  for (int i = 0; i < 8; ++i) acc_o[i] = z4;
  float m_st = -INFINITY, l_st = 0.f;
  char* Pw = Ps + w * 2048;

  for (int jt = 0; jt <= qt; ++jt) {
    const int j0 = jt * 64;
    __syncthreads();
    #pragma unroll
    for (int s = 0; s < 4; ++s) {
      int c = tid + s * 256;
      int row = c >> 4, sl = c & 15;
      int4 v = *(const int4*)(Kg + (size_t)(j0 + row) * 512 + kvh * 128 + sl * 8);
      *(int4*)(Ks + row * 256 + ((sl * 16) ^ ((row & 7) << 4))) = v;
    }
    #pragma unroll
    for (int s = 0; s < 4; ++s) {
      int c = tid + s * 256;
      int row = c >> 3, sl = c & 7;       // d-row, kv chunk
      int4 v = *(const int4*)(Vtg + (size_t)(kvh * 128 + row) * 2048 + j0 + sl * 8);
      *(int4*)(Vs + row * 128 + ((sl * 16) ^ ((row & 7) << 4))) = v;
    }
    {
      int row = tid >> 2, sl = tid & 3;
      int4 v = *(const int4*)(Bg + (size_t)(j0 + row) * 32 + sl * 8);
      *(int4*)(Bs_ + row * 80 + sl * 16) = v;
    }
    __syncthreads();

    // S^T = K . Q^T and md = Bm . A^T
    f32x4 acc_s[4], md[4];
    #pragma unroll
    for (int cb = 0; cb < 4; ++cb) {
      acc_s[cb] = z4;
      #pragma unroll
      for (int kk = 0; kk < 4; ++kk) {
        bf16x8 kf = *(const bf16x8*)(Ks + (cb * 16 + lr) * 256 +
                                     ((kk * 64 + g4 * 16) ^ ((lr & 7) << 4)));
        acc_s[cb] = MFMA16(kf, qf[kk], acc_s[cb], 0, 0, 0);
      }
      bf16x8 bmf = *(const bf16x8*)(Bs_ + (cb * 16 + lr) * 80 + g4 * 16);
      md[cb] = MFMA16(bmf, afr, z4, 0, 0, 0);
    }

    // bias + causal mask + online softmax (row = q = lr; 4 lanes share row)
    const int qi = q0 + w * 16 + lr;
    float mx = -INFINITY;
    #pragma unroll
    for (int cb = 0; cb < 4; ++cb)
      #pragma unroll
      for (int r = 0; r < 4; ++r) {
        int kj = j0 + cb * 16 + g4 * 4 + r;
        float sv;
        if (kj > qi) sv = -INFINITY;
        else {
          float delta = (float)(qi - kj);
          float sig = 1.f / (1.f + __expf(-md[cb][r]));
          sv = acc_s[cb][r] * sc - pol * delta * (1.f / 4096.f) - gamma * delta
               + gate * sig;
        }
        acc_s[cb][r] = sv;
        mx = fmaxf(mx, sv);
      }
    mx = fmaxf(mx, __shfl_xor(mx, 16));
    mx = fmaxf(mx, __shfl_xor(mx, 32));
    float mn = fmaxf(m_st, mx);
    float es = __expf(m_st - mn);
    float rs = 0.f;
    #pragma unroll
    for (int cb = 0; cb < 4; ++cb)
      #pragma unroll
      for (int r = 0; r < 4; ++r) {
        float p = __expf(acc_s[cb][r] - mn);
        acc_s[cb][r] = p;
        rs += p;
      }
    rs += __shfl_xor(rs, 16);
    rs += __shfl_xor(rs, 32);
    l_st = l_st * es + rs;
    m_st = mn;
    float es4[4];
    #pragma unroll
    for (int r = 0; r < 4; ++r) es4[r] = __shfl(es, g4 * 4 + r, 64);
    #pragma unroll
    for (int db = 0; db < 8; ++db)
      #pragma unroll
      for (int r = 0; r < 4; ++r) acc_o[db][r] *= es4[r];

    // P -> LDS (bf16, swizzled), then PV
    #pragma unroll
    for (int cb = 0; cb < 4; ++cb) {
      uint2 uu;
      uu.x = packbf(acc_s[cb][0], acc_s[cb][1]);
      uu.y = packbf(acc_s[cb][2], acc_s[cb][3]);
      *(uint2*)(Pw + lr * 128 + ((cb * 32 + g4 * 8) ^ ((lr & 7) << 4))) = uu;
    }
    asm volatile("s_waitcnt lgkmcnt(0)" ::: "memory");
    __builtin_amdgcn_sched_barrier(0);
    #pragma unroll
    for (int kk = 0; kk < 2; ++kk) {
      bf16x8 pf = *(const bf16x8*)(Pw + lr * 128 +
                                   ((kk * 64 + g4 * 16) ^ ((lr & 7) << 4)));
      #pragma unroll
      for (int db = 0; db < 8; ++db) {
        bf16x8 vf = *(const bf16x8*)(Vs + (db * 16 + lr) * 128 +
                                     ((kk * 64 + g4 * 16) ^ ((lr & 7) << 4)));
        acc_o[db] = MFMA16(pf, vf, acc_o[db], 0, 0, 0);
      }
    }
  }

  // epilogue: normalize, store bf16 AO. acc rows q = g4*4+r, col d = db*16+lr.
  float lrcp[4];
  #pragma unroll
  for (int r = 0; r < 4; ++r) lrcp[r] = 1.f / __shfl(l_st, g4 * 4 + r, 64);
  #pragma unroll
  for (int db = 0; db < 8; ++db)
    #pragma unroll
    for (int r = 0; r < 4; ++r)
      AO[(size_t)(q0 + w * 16 + g4 * 4 + r) * 2048 + h * 128 + db * 16 + lr] =
          f2bf(acc_o[db][r] * lrcp[r]);
}

// ---------------------------------------------------------------------------
// Launch
// ---------------------------------------------------------------------------
extern "C" void kernel_launch(void* const* d_in, const int* in_sizes, int n_in,
                              void* d_out, int out_size, void* d_ws, size_t ws_size,
                              hipStream_t stream) {
  const float* x         = (const float*)d_in[0];
  const float* Wq        = (const float*)d_in[1];
  const float* Wk        = (const float*)d_in[2];
  const float* Wv        = (const float*)d_in[3];
  const float* Wo        = (const float*)d_in[4];
  const float* pol_dir   = (const float*)d_in[5];
  const float* pol_WA    = (const float*)d_in[6];
  const float* pol_WB    = (const float*)d_in[7];
  const float* pol_gate  = (const float*)d_in[8];
  const float* gtp_gamma = (const float*)d_in[9];
  float* out = (float*)d_out;

  char* ws = (char*)d_ws;
  short* Qb   = (short*)(ws);                    // 2048x2048 bf16 = 8 MB
  short* Kb   = (short*)(ws + 8388608);          // 2048x512  bf16 = 2 MB
  short* Vtb  = (short*)(ws + 10485760);         // 512x2048  bf16 = 2 MB (V^T)
  short* Ab   = (short*)(ws + 12582912);         // 2048x32   bf16 = 128 KB
  short* Bb   = (short*)(ws + 12713984);         // 2048x32   bf16 = 128 KB
  short* xb   = (short*)(ws + 12845056);         // 8 MB (later reused as Wot)
  short* Wot  = xb;                              // written after gemm_qkv done
  short* Wqt  = (short*)(ws + 21233664);         // 8 MB (later reused as AO)
  short* AO   = Wqt;                             // written after gemm_qkv done
  short* Wkt  = (short*)(ws + 29622272);         // 2 MB
  short* Wvt  = (short*)(ws + 31719424);         // 2 MB
  short* WABt = (short*)(ws + 33816576);         // 128x2048 bf16 = 512 KB
  // total 34.3 MB (round-1 layout used 42.5 MB successfully)

  convert_f32_bf16<<<4096, 256, 0, stream>>>(x, xb, 1048576);
  transpose_f32_bf16<<<dim3(64, 64), 256, 0, stream>>>(Wq, Wqt, 2048, 2048);
  transpose_f32_bf16<<<dim3(16, 64), 256, 0, stream>>>(Wk, Wkt, 2048, 512);
  transpose_f32_bf16<<<dim3(16, 64), 256, 0, stream>>>(Wv, Wvt, 2048, 512);
  transpose_f32_bf16<<<dim3(1, 64), 256, 0, stream>>>(pol_WA, WABt, 2048, 32);
  transpose_f32_bf16<<<dim3(1, 64), 256, 0, stream>>>(pol_WB, WABt + 32 * 2048, 2048, 32);
  gemm_qkv_kernel<<<dim3(25, 16), 256, 0, stream>>>(xb, Wqt, Wkt, Wvt, WABt,
                                                    Qb, Kb, Vtb, Ab, Bb);
  rope_kernel<<<10240, 256, 0, stream>>>(Qb, Kb);
  transpose_f32_bf16<<<dim3(64, 64), 256, 0, stream>>>(Wo, Wot, 2048, 2048);
  attn_kernel<<<dim3(32, 16), 256, 0, stream>>>(Qb, Kb, Vtb, Ab, Bb,
                                                pol_dir, pol_gate, gtp_gamma, AO);
  gemm_out_kernel<<<dim3(16, 16), 256, 0, stream>>>(AO, Wot, out);
}